// Round 9
// baseline (151.128 us; speedup 1.0000x reference)
//
#include <hip/hip_runtime.h>
#include <hip/hip_fp16.h>

typedef float f2v __attribute__((ext_vector_type(2)));

// 24B packed row: 10 x f16 (20B) + 4B pad, 8B-aligned. As table = 2.4MB.
struct __attribute__((packed, aligned(8))) Row24 {
    uint2 ab;   // h0..h3
    uint2 cd;   // h4..h7
    uint  e;    // h8..h9
    uint  pad;
};

__device__ __forceinline__ float2 h2f2(uint v) {
    __half2 h = *(__half2*)&v;
    return __half22float2(h);
}

// ---- prep: A_s[n] = x_s[n] @ W1[0:10,:]  -> f16 Row24 (2.4 MB) ----
__global__ __launch_bounds__(256) void prep_as(const float* __restrict__ xs,
                                               const float* __restrict__ W1,
                                               Row24* __restrict__ As, int N) {
    const int n = blockIdx.x * 256 + threadIdx.x;
    if (n >= N) return;
    float f[10];
    const float2* p = (const float2*)(xs + (size_t)n * 10);
    #pragma unroll
    for (int i = 0; i < 5; ++i) { float2 v = p[i]; f[2 * i] = v.x; f[2 * i + 1] = v.y; }
    float a[10];
    #pragma unroll
    for (int j = 0; j < 10; ++j) a[j] = 0.f;
    #pragma unroll
    for (int k = 0; k < 10; ++k) {
        const float fk = f[k];
        #pragma unroll
        for (int j = 0; j < 10; ++j) a[j] += fk * W1[k * 10 + j];   // uniform -> s_load
    }
    uint q[5];
    #pragma unroll
    for (int i = 0; i < 5; ++i) {
        __half2 h = __floats2half2_rn(a[2 * i], a[2 * i + 1]);
        q[i] = *(uint*)&h;
    }
    Row24 r;
    r.ab = make_uint2(q[0], q[1]);
    r.cd = make_uint2(q[2], q[3]);
    r.e  = q[4];
    r.pad = 0;
    As[n] = r;
}

// ---- prep: x_t[n] -> 5 x f16 packed into 16B (one dwordx4 gather; 1.6 MB) ----
__global__ __launch_bounds__(256) void prep_xt(const float* __restrict__ xt,
                                               uint4* __restrict__ Xt, int N) {
    const int n = blockIdx.x * 256 + threadIdx.x;
    if (n >= N) return;
    float f[5];
    #pragma unroll
    for (int i = 0; i < 5; ++i) f[i] = xt[(size_t)n * 5 + i];
    __half2 h01 = __floats2half2_rn(f[0], f[1]);
    __half2 h23 = __floats2half2_rn(f[2], f[3]);
    __half2 h4_ = __floats2half2_rn(f[4], 0.f);
    uint4 r;
    r.x = *(uint*)&h01;
    r.y = *(uint*)&h23;
    r.z = *(uint*)&h4_;
    r.w = 0;
    Xt[n] = r;
}

// ---- main: software-pipelined grid-stride loop, ~8 edges/thread.
//      idx prefetched at distance 2, gathers + ea stream at distance 1. ----
__global__ __launch_bounds__(256) void edge_mlp_pipe(
    const Row24* __restrict__ As,
    const uint4* __restrict__ Xt,
    const int* __restrict__ src,
    const int* __restrict__ tgt,
    const float* __restrict__ ea,
    const float* __restrict__ u,
    const int* __restrict__ be,
    const float* __restrict__ W1,
    const float* __restrict__ b1,
    const float* __restrict__ W2,
    const float* __restrict__ b2,
    float* __restrict__ out, int E)
{
    __shared__ float sUp[16 * 12];    // U' = u @ W1[25:35] + b1

    const int t = threadIdx.x;
    if (t < 160) {
        const int b = t / 10, j = t % 10;
        float acc = b1[j];
        #pragma unroll
        for (int k = 0; k < 10; ++k) acc += u[b * 10 + k] * W1[(25 + k) * 10 + j];
        sUp[b * 12 + j] = acc;
    }
    __syncthreads();

    const long long stride = (long long)gridDim.x * 256;
    long long e_cur = (long long)blockIdx.x * 256 + t;
    if (e_cur >= E) return;

    // ---- prologue: fill the pipeline ----
    int is0 = __builtin_nontemporal_load(src + e_cur);
    int it0 = __builtin_nontemporal_load(tgt + e_cur);
    int ib0 = __builtin_nontemporal_load(be + e_cur);

    long long e_nxt = e_cur + stride;
    long long c1 = (e_nxt < E) ? e_nxt : (long long)(E - 1);
    int is1 = __builtin_nontemporal_load(src + c1);
    int it1 = __builtin_nontemporal_load(tgt + c1);
    int ib1 = __builtin_nontemporal_load(be + c1);

    Row24 ra0 = As[is0];
    uint4 rt0 = Xt[it0];
    f2v g0[5];
    {
        const f2v* pe = (const f2v*)(ea + e_cur * 10);
        #pragma unroll
        for (int i = 0; i < 5; ++i) g0[i] = __builtin_nontemporal_load(pe + i);
    }

    for (;;) {
        // ---- issue idx[n+2], gathers[n+1], ea[n+1] ----
        long long e_n2 = e_nxt + stride;
        long long c2 = (e_n2 < E) ? e_n2 : (long long)(E - 1);
        int is2 = __builtin_nontemporal_load(src + c2);
        int it2 = __builtin_nontemporal_load(tgt + c2);
        int ib2 = __builtin_nontemporal_load(be + c2);

        Row24 ra1 = As[is1];
        uint4 rt1 = Xt[it1];
        f2v g1[5];
        {
            const f2v* pe = (const f2v*)(ea + c1 * 10);
            #pragma unroll
            for (int i = 0; i < 5; ++i) g1[i] = __builtin_nontemporal_load(pe + i);
        }

        // ---- compute edge e_cur (all operands in registers/L2-hit LDS) ----
        float h[10];
        {
            uint qa[5] = { ra0.ab.x, ra0.ab.y, ra0.cd.x, ra0.cd.y, ra0.e };
            #pragma unroll
            for (int i = 0; i < 5; ++i) {
                float2 a2 = h2f2(qa[i]);
                h[2 * i]     = a2.x + sUp[ib0 * 12 + 2 * i];
                h[2 * i + 1] = a2.y + sUp[ib0 * 12 + 2 * i + 1];
            }
        }
        {
            float2 t01 = h2f2(rt0.x), t23 = h2f2(rt0.y), t4_ = h2f2(rt0.z);
            const float tv[5] = { t01.x, t01.y, t23.x, t23.y, t4_.x };
            #pragma unroll
            for (int k = 0; k < 5; ++k) {
                const float fk = tv[k];
                #pragma unroll
                for (int j = 0; j < 10; ++j) h[j] += fk * W1[(10 + k) * 10 + j];
            }
        }
        #pragma unroll
        for (int k = 0; k < 10; ++k) {
            const float gk = g0[k >> 1][k & 1];
            #pragma unroll
            for (int j = 0; j < 10; ++j) h[j] += gk * W1[(15 + k) * 10 + j];
        }
        #pragma unroll
        for (int j = 0; j < 10; ++j) h[j] = (h[j] >= 0.f) ? h[j] : 0.1f * h[j];

        float o[10];
        #pragma unroll
        for (int j = 0; j < 10; ++j) o[j] = b2[j];
        #pragma unroll
        for (int k = 0; k < 10; ++k) {
            const float hk = h[k];
            #pragma unroll
            for (int j = 0; j < 10; ++j) o[j] += hk * W2[k * 10 + j];
        }

        float2* po = (float2*)(out + e_cur * 10);
        #pragma unroll
        for (int i = 0; i < 5; ++i) {
            float2 v; v.x = o[2 * i]; v.y = o[2 * i + 1];
            po[i] = v;
        }

        if (e_nxt >= E) break;
        // ---- shift pipeline ----
        e_cur = e_nxt; e_nxt = e_n2; c1 = c2;
        ra0 = ra1; rt0 = rt1; ib0 = ib1;
        is1 = is2; it1 = it2; ib1 = ib2;
        #pragma unroll
        for (int i = 0; i < 5; ++i) g0[i] = g1[i];
    }
}

// ---- fallback (ws too small): direct compute from raw tables ----
__global__ __launch_bounds__(256) void edge_mlp_raw(
    const float* __restrict__ xs, const float* __restrict__ xt,
    const int* __restrict__ src, const int* __restrict__ tgt,
    const float* __restrict__ ea, const float* __restrict__ u,
    const int* __restrict__ be,
    const float* __restrict__ W1, const float* __restrict__ b1,
    const float* __restrict__ W2, const float* __restrict__ b2,
    float* __restrict__ out, int E)
{
    __shared__ float sUp[16 * 12];
    const int t = threadIdx.x;
    if (t < 160) {
        const int b = t / 10, j = t % 10;
        float acc = b1[j];
        #pragma unroll
        for (int k = 0; k < 10; ++k) acc += u[b * 10 + k] * W1[(25 + k) * 10 + j];
        sUp[b * 12 + j] = acc;
    }
    __syncthreads();
    const int e = blockIdx.x * 256 + t;
    if (e >= E) return;
    const int is = src[e], it = tgt[e], ib = be[e];
    float f[25];
    const float* ps = xs + (size_t)is * 10;
    #pragma unroll
    for (int i = 0; i < 5; ++i) {
        float2 v = *(const float2*)(ps + 2 * i);
        f[2 * i] = v.x; f[2 * i + 1] = v.y;
    }
    const float* pt = xt + (size_t)it * 5;
    #pragma unroll
    for (int i = 0; i < 5; ++i) f[10 + i] = pt[i];
    const float2* pe = (const float2*)(ea + (size_t)e * 10);
    #pragma unroll
    for (int i = 0; i < 5; ++i) { float2 v = pe[i]; f[15 + 2 * i] = v.x; f[16 + 2 * i] = v.y; }
    float h[10];
    #pragma unroll
    for (int j = 0; j < 10; ++j) h[j] = sUp[ib * 12 + j];
    #pragma unroll
    for (int k = 0; k < 25; ++k) {
        const float fk = f[k];
        #pragma unroll
        for (int j = 0; j < 10; ++j) h[j] += fk * W1[k * 10 + j];
    }
    #pragma unroll
    for (int j = 0; j < 10; ++j) h[j] = (h[j] >= 0.f) ? h[j] : 0.1f * h[j];
    float o[10];
    #pragma unroll
    for (int j = 0; j < 10; ++j) o[j] = b2[j];
    #pragma unroll
    for (int k = 0; k < 10; ++k) {
        const float hk = h[k];
        #pragma unroll
        for (int j = 0; j < 10; ++j) o[j] += hk * W2[k * 10 + j];
    }
    float2* po = (float2*)(out + (size_t)e * 10);
    #pragma unroll
    for (int i = 0; i < 5; ++i) { float2 v; v.x = o[2 * i]; v.y = o[2 * i + 1]; po[i] = v; }
}

extern "C" void kernel_launch(void* const* d_in, const int* in_sizes, int n_in,
                              void* d_out, int out_size, void* d_ws, size_t ws_size,
                              hipStream_t stream) {
    const float* x_s      = (const float*)d_in[0];
    const float* x_t      = (const float*)d_in[1];
    const int*   ei       = (const int*)d_in[2];    // (2, E) flat: [src | tgt]
    const float* edge_att = (const float*)d_in[3];
    const float* u        = (const float*)d_in[4];
    const int*   batch_e  = (const int*)d_in[5];
    const float* W1       = (const float*)d_in[6];
    const float* b1       = (const float*)d_in[7];
    const float* W2       = (const float*)d_in[8];
    const float* b2       = (const float*)d_in[9];
    float* out = (float*)d_out;

    const int E   = in_sizes[5];
    const int N_S = in_sizes[0] / 10;
    const int N_T = in_sizes[1] / 5;

    const size_t need = (size_t)N_S * sizeof(Row24) + (size_t)N_T * sizeof(uint4);
    if (ws_size >= need) {
        Row24* As = (Row24*)d_ws;
        uint4* Xt = (uint4*)((char*)d_ws + (size_t)N_S * sizeof(Row24));
        prep_as<<<(N_S + 255) / 256, 256, 0, stream>>>(x_s, W1, As, N_S);
        prep_xt<<<(N_T + 255) / 256, 256, 0, stream>>>(x_t, Xt, N_T);
        const int blocks = (E + 2047) / 2048;   // ~8 edges/thread
        edge_mlp_pipe<<<blocks, 256, 0, stream>>>(
            As, Xt, ei, ei + E, edge_att, u, batch_e,
            W1, b1, W2, b2, out, E);
    } else {
        const int blocks = (E + 255) / 256;
        edge_mlp_raw<<<blocks, 256, 0, stream>>>(
            x_s, x_t, ei, ei + E, edge_att, u, batch_e,
            W1, b1, W2, b2, out, E);
    }
}